// Round 1
// 1224.663 us; speedup vs baseline: 1.0301x; 1.0301x over previous
//
#include <hip/hip_runtime.h>
#include <hip/hip_bf16.h>
#include <stdint.h>
#include <stddef.h>

// Swin WindowAttention, MI355X gfx950.
// B_=4096 windows, N=49, C=384, H=12, hd=32, num_win=64. M = 200704.
// Pipeline: convert(fp32->bf16) -> cmb(bias+mask precompute) ->
//           qkv GEMM (bf16 MFMA) -> per-(b,h) wave attention -> proj GEMM.
// R1: gemm_nt gets (a) 2-phase double-buffered LDS pipeline with counted
//     vmcnt + raw s_barrier (no __syncthreads drain in K-loop),
//     (b) XCD-aware block swizzle (A panel fetched once per XCD),
//     (c) LDS-staged vectorized bf16 epilogue (16B coalesced stores).

typedef __attribute__((ext_vector_type(8))) __bf16 bf16x8;
typedef __attribute__((ext_vector_type(4))) float f32x4;
typedef __attribute__((ext_vector_type(4))) unsigned short u16x4;
typedef __attribute__((ext_vector_type(8))) unsigned short u16x8;

typedef const unsigned int __attribute__((address_space(1)))* gptr_t;
typedef unsigned int __attribute__((address_space(3)))* lptr_t;

#define SCALE 0.17677669529663687f   // 32^-0.5

__device__ __forceinline__ unsigned short f2bf(float f) {
  union { float f; unsigned int u; } c; c.f = f;
  unsigned int r = c.u + 0x7fffu + ((c.u >> 16) & 1u);   // RNE
  return (unsigned short)(r >> 16);
}

__device__ __forceinline__ void gl_lds16(const void* g, void* s) {
  // async global->LDS, 16B per lane, LDS dest = wave-uniform base + lane*16
  __builtin_amdgcn_global_load_lds((gptr_t)g, (lptr_t)s, 16, 0, 0);
}

// ---------------- kernel 1: fp32 -> bf16 bulk convert ----------------
__global__ __launch_bounds__(256) void convert_kernel(
    const float* __restrict__ x, unsigned short* __restrict__ xb, long nx4,
    const float* __restrict__ w1, unsigned short* __restrict__ w1b, long n14,
    const float* __restrict__ w2, unsigned short* __restrict__ w2b, long n24) {
  long stride = (long)gridDim.x * blockDim.x;
  long t0 = (long)blockIdx.x * blockDim.x + threadIdx.x;
  for (long i = t0; i < nx4; i += stride) {
    f32x4 v = ((const f32x4*)x)[i];
    u16x4 o;
#pragma unroll
    for (int j = 0; j < 4; ++j) o[j] = f2bf(v[j]);
    ((u16x4*)xb)[i] = o;
  }
  for (long i = t0; i < n14; i += stride) {
    f32x4 v = ((const f32x4*)w1)[i];
    u16x4 o;
#pragma unroll
    for (int j = 0; j < 4; ++j) o[j] = f2bf(v[j]);
    ((u16x4*)w1b)[i] = o;
  }
  for (long i = t0; i < n24; i += stride) {
    f32x4 v = ((const f32x4*)w2)[i];
    u16x4 o;
#pragma unroll
    for (int j = 0; j < 4; ++j) o[j] = f2bf(v[j]);
    ((u16x4*)w2b)[i] = o;
  }
}

// ---------------- kernel 2: cmb[w][h][64][64] = bias + mask, pad=-1e30 ----
__global__ __launch_bounds__(256) void cmb_kernel(
    const float* __restrict__ mask, const float* __restrict__ bias_table,
    const int* __restrict__ rel_index, float* __restrict__ cmb) {
  int idx = blockIdx.x * 256 + threadIdx.x;        // 64*12*64*64 = 3145728 exact
  int j = idx & 63, i = (idx >> 6) & 63;
  int hw = idx >> 12;
  int h = hw % 12, w = hw / 12;
  float v = -1e30f;
  if (i < 49 && j < 49)
    v = bias_table[rel_index[i * 49 + j] * 12 + h] + mask[(w * 49 + i) * 49 + j];
  cmb[idx] = v;
}

// ---------------- NT GEMM: C[M,Nn] = A[M,K] * Bw[Nn,K]^T + bias ----------
// 128x128 tile, BK=32, 4 waves (2x2), 16x16x32 bf16 MFMA, global_load_lds.
// Double-buffered LDS, 2-phase pipeline: stage(t+1) issued before compute(t),
// s_waitcnt vmcnt(4) (current tile done, next tile in flight), raw barriers.
// LDS chunk swizzle (unchanged): chunk q of row r lives at q ^ ((r>>1)&3).
// Grid must be divisible by 8 (XCD swizzle).
template <int NBN, int KDIM, bool OUT_BF16>
__global__ __launch_bounds__(256) void gemm_nt(
    const unsigned short* __restrict__ A, const unsigned short* __restrict__ Bw,
    const float* __restrict__ bias, unsigned short* __restrict__ Cb,
    float* __restrict__ Cf, int Nn) {
  // Sm layout: [0,4096)=As buf0, [4096,8192)=As buf1,
  //            [8192,12288)=Bs buf0, [12288,16384)=Bs buf1.
  // Epilogue (bf16 path) reuses Sm[0..8448) as a 64x132 staging tile.
  __shared__ __align__(16) unsigned short Sm[16384];
  const int tid = threadIdx.x;
  const int w = tid >> 6, l = tid & 63, q = l >> 4, ln = l & 15;
  // XCD-aware swizzle: consecutive blockIdx round-robin XCDs; remap so each
  // XCD owns a contiguous tile range -> all NBN bn-blocks of a bm panel
  // share one XCD's L2 (A panel fetched once per XCD).
  const int cpx = gridDim.x >> 3;                  // gridDim.x % 8 == 0
  const int swz = (blockIdx.x & 7) * cpx + (blockIdx.x >> 3);
  const int bm = swz / NBN, bn = swz % NBN;
  const unsigned short* Ab = A + (size_t)bm * 128 * KDIM;
  const unsigned short* Bb = Bw + (size_t)bn * 128 * KDIM;
  const int wm = w >> 1, wn = w & 1;
  const int lrow = l >> 2;                       // row within 16-row group
  const int lch = (l & 3) ^ ((l >> 3) & 3);      // swizzled source k-chunk

  // bias loads issued before the K-loop so in-loop vmcnt counts are clean
  float bv[4];
#pragma unroll
  for (int j = 0; j < 4; ++j) bv[j] = bias[bn * 128 + wn * 64 + j * 16 + ln];

  // stage one 128x32 A-tile + B-tile into buffer `buf` (4 gl_lds per lane)
  auto stage = [&](int buf, int k0) {
    unsigned short* as = Sm + buf * 4096;
    unsigned short* bs = Sm + 8192 + buf * 4096;
#pragma unroll
    for (int i = 0; i < 2; ++i) {
      int rowbase = (w * 2 + i) * 16;
      gl_lds16(Ab + (size_t)(rowbase + lrow) * KDIM + k0 + lch * 8,
               &as[rowbase * 32]);
      gl_lds16(Bb + (size_t)(rowbase + lrow) * KDIM + k0 + lch * 8,
               &bs[rowbase * 32]);
    }
  };

  f32x4 acc[4][4] = {};
  const int ch = q ^ ((ln >> 1) & 3);
  constexpr int NIT = KDIM / 32;
  stage(0, 0);
  int cur = 0;
#pragma unroll
  for (int t = 0; t < NIT; ++t) {
    if (t + 1 < NIT) {
      stage(cur ^ 1, (t + 1) * 32);              // prefetch next tile
      asm volatile("s_waitcnt vmcnt(4)" ::: "memory");   // cur tile landed
    } else {
      asm volatile("s_waitcnt vmcnt(0)" ::: "memory");
    }
    __builtin_amdgcn_s_barrier();                // all waves' cur tile visible
    const unsigned short* as = Sm + cur * 4096;
    const unsigned short* bs = Sm + 8192 + cur * 4096;
    bf16x8 af[4], bf[4];
#pragma unroll
    for (int tt = 0; tt < 4; ++tt) {
      af[tt] = *(const bf16x8*)&as[(wm * 64 + tt * 16 + ln) * 32 + ch * 8];
      bf[tt] = *(const bf16x8*)&bs[(wn * 64 + tt * 16 + ln) * 32 + ch * 8];
    }
#pragma unroll
    for (int i = 0; i < 4; ++i)
#pragma unroll
      for (int j = 0; j < 4; ++j)
        acc[i][j] = __builtin_amdgcn_mfma_f32_16x16x32_bf16(af[i], bf[j],
                                                            acc[i][j], 0, 0, 0);
    asm volatile("s_waitcnt lgkmcnt(0)" ::: "memory");   // my ds_reads done
    __builtin_amdgcn_s_barrier();                // buf[cur] safe to overwrite
    cur ^= 1;
  }

  // epilogue: C/D layout col=lane&15, row=quad*4+reg
  if constexpr (OUT_BF16) {
    // Two-pass LDS transpose-stage: 64 rows x 132 (pad +4 -> quads 8 banks
    // apart, conflict-free b16 writes; 264B rows keep 8B alignment for b64
    // reads). Then 16B fully-coalesced global stores (256B per 16 lanes).
    const int rr = tid >> 4, c8 = (tid & 15) * 8;
    const size_t crow = (size_t)bm * 128;
#pragma unroll
    for (int half = 0; half < 2; ++half) {
      if (wm == half) {
#pragma unroll
        for (int j = 0; j < 4; ++j) {
          int col = wn * 64 + j * 16 + ln;
#pragma unroll
          for (int i = 0; i < 4; ++i) {
            int r0 = i * 16 + q * 4;
#pragma unroll
            for (int r = 0; r < 4; ++r)
              Sm[(r0 + r) * 132 + col] = f2bf(acc[i][j][r] + bv[j]);
          }
        }
      }
      __syncthreads();
#pragma unroll
      for (int p = 0; p < 4; ++p) {
        int row = p * 16 + rr;
        u16x4 v0 = *(const u16x4*)&Sm[row * 132 + c8];
        u16x4 v1 = *(const u16x4*)&Sm[row * 132 + c8 + 4];
        u16x8 v;
#pragma unroll
        for (int k = 0; k < 4; ++k) { v[k] = v0[k]; v[4 + k] = v1[k]; }
        *(u16x8*)&Cb[(crow + half * 64 + row) * Nn + bn * 128 + c8] = v;
      }
      if (half == 0) __syncthreads();
    }
  } else {
    // fp32 out: scalar dword stores are already 64B/quad coalesced
#pragma unroll
    for (int j = 0; j < 4; ++j) {
      int col = bn * 128 + wn * 64 + j * 16 + ln;
#pragma unroll
      for (int i = 0; i < 4; ++i) {
        int row0 = bm * 128 + wm * 64 + i * 16 + q * 4;
#pragma unroll
        for (int r = 0; r < 4; ++r)
          Cf[(size_t)(row0 + r) * Nn + col] = acc[i][j][r] + bv[j];
      }
    }
  }
}

// ---------------- kernel 4: attention, one wave per (window b, head h) -----
// qkv row m = b*49+n, col: q at h*32+d, k at 384+h*32+d, v at 768+h*32+d
__global__ __launch_bounds__(256) void attn_kernel(
    const unsigned short* __restrict__ qkv, const float* __restrict__ cmb,
    unsigned short* __restrict__ aout) {
  __shared__ __align__(16) unsigned short Ps[4][64 * 80];   // per-wave P, pad 80
  const int tid = threadIdx.x;
  const int w = tid >> 6, l = tid & 63, q = l >> 4, ln = l & 15;
  const int pair = blockIdx.x * 4 + w;     // 0..49151
  const int b = pair / 12, h = pair % 12;
  const int win = b & 63;
  const unsigned short* base = qkv + (size_t)b * 49 * 1152 + h * 32;
  // Q (A-op) and K (B-op) frags: lane holds [l&15 row][quad*8 k-chunk], 16B
  bf16x8 qf[4], kf[4];
#pragma unroll
  for (int t = 0; t < 4; ++t) {
    int r = t * 16 + ln;
    int rr = (r < 49) ? r : 0;             // clamp pad rows (masked later)
    qf[t] = *(const bf16x8*)(base + (size_t)rr * 1152 + q * 8);
    kf[t] = *(const bf16x8*)(base + 384 + (size_t)rr * 1152 + q * 8);
  }
  f32x4 s[4][4] = {};
#pragma unroll
  for (int i = 0; i < 4; ++i)
#pragma unroll
    for (int j = 0; j < 4; ++j)
      s[i][j] = __builtin_amdgcn_mfma_f32_16x16x32_bf16(qf[i], kf[j], s[i][j],
                                                        0, 0, 0);
  // scale + bias + mask, rowwise softmax (row lives in one 16-lane quad group)
  const float* cb = cmb + ((size_t)win * 12 + h) * 4096;
#pragma unroll
  for (int mt = 0; mt < 4; ++mt) {
#pragma unroll
    for (int r = 0; r < 4; ++r) {
      int row = mt * 16 + q * 4 + r;
      float v[4];
#pragma unroll
      for (int nt = 0; nt < 4; ++nt)
        v[nt] = s[mt][nt][r] * SCALE + cb[row * 64 + nt * 16 + ln];
      float m = fmaxf(fmaxf(v[0], v[1]), fmaxf(v[2], v[3]));
#pragma unroll
      for (int off = 1; off < 16; off <<= 1)
        m = fmaxf(m, __shfl_xor(m, off, 64));
      float p[4], sum = 0.f;
#pragma unroll
      for (int nt = 0; nt < 4; ++nt) { p[nt] = __expf(v[nt] - m); sum += p[nt]; }
#pragma unroll
      for (int off = 1; off < 16; off <<= 1)
        sum += __shfl_xor(sum, off, 64);
      float inv = 1.0f / sum;
#pragma unroll
      for (int nt = 0; nt < 4; ++nt)
        Ps[w][row * 80 + nt * 16 + ln] = f2bf(p[nt] * inv);
    }
  }
  __syncthreads();   // P C/D-layout -> A-layout via LDS round trip
  // V as B-operand of PV: lane needs V[j = kt*32+quad*8+jj][d = nt*16+ln]
  const __bf16* vbase = (const __bf16*)(base + 768);
  bf16x8 vf[2][2];
#pragma unroll
  for (int nt = 0; nt < 2; ++nt)
#pragma unroll
    for (int kt = 0; kt < 2; ++kt) {
      bf16x8 tmp;
#pragma unroll
      for (int jj = 0; jj < 8; ++jj) {
        int j = kt * 32 + q * 8 + jj;
        int jc = (j < 49) ? j : 0;         // pad P cols are exactly 0
        tmp[jj] = vbase[(size_t)jc * 1152 + nt * 16 + ln];
      }
      vf[nt][kt] = tmp;
    }
  f32x4 o[4][2] = {};
#pragma unroll
  for (int mt = 0; mt < 4; ++mt)
#pragma unroll
    for (int kt = 0; kt < 2; ++kt) {
      bf16x8 pf = *(const bf16x8*)&Ps[w][(mt * 16 + ln) * 80 + kt * 32 + q * 8];
#pragma unroll
      for (int nt = 0; nt < 2; ++nt)
        o[mt][nt] = __builtin_amdgcn_mfma_f32_16x16x32_bf16(pf, vf[nt][kt],
                                                            o[mt][nt], 0, 0, 0);
    }
#pragma unroll
  for (int mt = 0; mt < 4; ++mt)
#pragma unroll
    for (int r = 0; r < 4; ++r) {
      int n = mt * 16 + q * 4 + r;
      if (n < 49) {
#pragma unroll
        for (int nt = 0; nt < 2; ++nt)
          aout[((size_t)b * 49 + n) * 384 + h * 32 + nt * 16 + ln] =
              f2bf(o[mt][nt][r]);
      }
    }
}

extern "C" void kernel_launch(void* const* d_in, const int* in_sizes, int n_in,
                              void* d_out, int out_size, void* d_ws,
                              size_t ws_size, hipStream_t stream) {
  (void)in_sizes; (void)n_in; (void)out_size; (void)ws_size;
  const float* x          = (const float*)d_in[0];
  const float* mask       = (const float*)d_in[1];
  const float* qkv_w      = (const float*)d_in[2];
  const float* qkv_b      = (const float*)d_in[3];
  const float* proj_w     = (const float*)d_in[4];
  const float* proj_b     = (const float*)d_in[5];
  const float* bias_table = (const float*)d_in[6];
  const int*   rel_index  = (const int*)d_in[7];

  char* ws = (char*)d_ws;
  // layout (bytes): qkv 462,422,016 | xb/aout 154,140,672 | wq 884,736 |
  //                 wp 294,912 | cmb 12,582,912  => total 630,325,248
  unsigned short* qkv  = (unsigned short*)ws;
  unsigned short* xb   = (unsigned short*)(ws + 462422016ull);
  unsigned short* aout = xb;   // xb dead after qkv GEMM; alias is ordered-safe
  unsigned short* wq   = (unsigned short*)(ws + 616562688ull);
  unsigned short* wp   = (unsigned short*)(ws + 617447424ull);
  float*          cmb  = (float*)(ws + 617742336ull);

  convert_kernel<<<2048, 256, 0, stream>>>(x, xb, 19267584L,
                                           qkv_w, wq, 110592L,
                                           proj_w, wp, 36864L);
  cmb_kernel<<<12288, 256, 0, stream>>>(mask, bias_table, rel_index, cmb);
  // qkv[M=200704, 1152] = xb @ wq^T + qkv_b   (1568 x 9 blocks, 14112 % 8 == 0)
  gemm_nt<9, 384, true><<<14112, 256, 0, stream>>>(xb, wq, qkv_b, qkv, nullptr,
                                                   1152);
  attn_kernel<<<12288, 256, 0, stream>>>(qkv, cmb, aout);
  // out[M, 384] = aout @ wp^T + proj_b        (1568 x 3 blocks, 4704 % 8 == 0)
  gemm_nt<3, 384, false><<<4704, 256, 0, stream>>>(aout, wp, proj_b, nullptr,
                                                   (float*)d_out, 384);
}